// Round 3
// baseline (145.983 us; speedup 1.0000x reference)
//
#include <hip/hip_runtime.h>

// Problem: B=8, T_en=T_de=D=U=256.
// out = de + softmax_e( sum_u tanh(att_en[b,e,u]+att_de[b,t,u]) * nu[u] ) @ en
// att_* = (en|de) @ w_*, PRESCALED by 2*log2(e) so tanh(x) = 1 - 2/(exp2(ae+ad)+1).

#define C2LOG2E 2.8853900817779268f   // 2*log2(e)
#define LOG2E   1.4426950408889634f

// Async global->LDS DMA, 16B per lane. dst MUST be wave-uniform base + lane*16.
__device__ __forceinline__ void g2lds16(const float* g, float* l) {
    __builtin_amdgcn_global_load_lds(
        (const __attribute__((address_space(1))) unsigned int*)g,
        (__attribute__((address_space(3))) unsigned int*)l, 16, 0, 0);
}

// ---------------------------------------------------------------------------
// att_en = (en @ w_en)*C, att_de = (de @ w_de)*C.
// 128 threads = 2 waves; wave owns 4 rows (wave-uniform -> s_load A),
// lanes span 256 cols (4/lane). B k-chunks of 32 rows double-buffered in LDS
// via global_load_lds (chunk is contiguous 32KB). grid (256, 2): x=row-block,
// y=matrix. 2 blocks/CU (64KB LDS).
// ---------------------------------------------------------------------------
__global__ __launch_bounds__(128) void gemm2(
    const float* __restrict__ en, const float* __restrict__ de,
    const float* __restrict__ w_en, const float* __restrict__ w_de,
    float* __restrict__ att_en, float* __restrict__ att_de)
{
    const float* x = blockIdx.y ? de : en;
    const float* w = blockIdx.y ? w_de : w_en;
    float* y       = blockIdx.y ? att_de : att_en;

    const int tid  = threadIdx.x;
    const int lane = tid & 63;
    const int wv   = __builtin_amdgcn_readfirstlane(tid >> 6);
    const int r0   = blockIdx.x * 8 + wv * 4;
    const int c0   = lane << 2;

    __shared__ float bs[2][32 * 256];   // 2 x 32KB

    const float* xr0 = x + (r0 + 0) * 256;
    const float* xr1 = x + (r0 + 1) * 256;
    const float* xr2 = x + (r0 + 2) * 256;
    const float* xr3 = x + (r0 + 3) * 256;

    float4 acc0{0,0,0,0}, acc1{0,0,0,0}, acc2{0,0,0,0}, acc3{0,0,0,0};

    // stage chunk 0: 8192 float4 / 128 thr = 16 calls each
    #pragma unroll
    for (int i = 0; i < 16; ++i)
        g2lds16(w + ((i * 128 + tid) << 2), &bs[0][(i * 128 + tid) << 2]);
    __syncthreads();

    for (int c = 0; c < 8; ++c) {
        const int k0 = c << 5;
        const float* bsc = bs[c & 1];
        if (c < 7) {
            const float* wn = w + ((k0 + 32) << 8);
            float* dst = bs[(c + 1) & 1];
            #pragma unroll
            for (int i = 0; i < 16; ++i)
                g2lds16(wn + ((i * 128 + tid) << 2), dst + ((i * 128 + tid) << 2));
        }
        #pragma unroll
        for (int g = 0; g < 8; ++g) {
            const int kk = k0 + (g << 2);
            const float4 a0 = *(const float4*)(xr0 + kk);  // wave-uniform
            const float4 a1 = *(const float4*)(xr1 + kk);
            const float4 a2 = *(const float4*)(xr2 + kk);
            const float4 a3 = *(const float4*)(xr3 + kk);
            const float* p0 = (const float*)&a0;
            const float* p1 = (const float*)&a1;
            const float* p2 = (const float*)&a2;
            const float* p3 = (const float*)&a3;
            #pragma unroll
            for (int j = 0; j < 4; ++j) {
                const float4 bv = *(const float4*)&bsc[((g << 2) + j) * 256 + c0];
                acc0.x = fmaf(p0[j], bv.x, acc0.x); acc0.y = fmaf(p0[j], bv.y, acc0.y);
                acc0.z = fmaf(p0[j], bv.z, acc0.z); acc0.w = fmaf(p0[j], bv.w, acc0.w);
                acc1.x = fmaf(p1[j], bv.x, acc1.x); acc1.y = fmaf(p1[j], bv.y, acc1.y);
                acc1.z = fmaf(p1[j], bv.z, acc1.z); acc1.w = fmaf(p1[j], bv.w, acc1.w);
                acc2.x = fmaf(p2[j], bv.x, acc2.x); acc2.y = fmaf(p2[j], bv.y, acc2.y);
                acc2.z = fmaf(p2[j], bv.z, acc2.z); acc2.w = fmaf(p2[j], bv.w, acc2.w);
                acc3.x = fmaf(p3[j], bv.x, acc3.x); acc3.y = fmaf(p3[j], bv.y, acc3.y);
                acc3.z = fmaf(p3[j], bv.z, acc3.z); acc3.w = fmaf(p3[j], bv.w, acc3.w);
            }
        }
        __syncthreads();
    }

    const float s = C2LOG2E;   // prescale for the attn tanh
    acc0.x *= s; acc0.y *= s; acc0.z *= s; acc0.w *= s;
    acc1.x *= s; acc1.y *= s; acc1.z *= s; acc1.w *= s;
    acc2.x *= s; acc2.y *= s; acc2.z *= s; acc2.w *= s;
    acc3.x *= s; acc3.y *= s; acc3.z *= s; acc3.w *= s;
    *(float4*)(y + (r0 + 0) * 256 + c0) = acc0;
    *(float4*)(y + (r0 + 1) * 256 + c0) = acc1;
    *(float4*)(y + (r0 + 2) * 256 + c0) = acc2;
    *(float4*)(y + (r0 + 3) * 256 + c0) = acc3;
}

// ---------------------------------------------------------------------------
// Attention. 256 threads = 4 waves. Block handles (b, t0..t0+1); wave wv:
// t = t0 + (wv&1), u-half = wv>>1 (both WAVE-UNIFORM -> att_de/nu via s_load).
// Stage 1: att_en staged in 64-row chunks by global_load_lds, float4 columns
//   XOR-swizzled (j_lds = j ^ (row&7)) for conflict-free lane=row b128 reads.
//   lane = e-row; per-lane register mu accumulation, no cross-lane reduce.
// Stage 2: waves 0,1 do softmax for t0,t1 (sum the two u-half partials).
// Stage 3: wave (t,h) accumulates alphas@en over its e-half; partials
//   combined through reused ae LDS.  grid: 1024 blocks, 2 blocks/CU.
// ---------------------------------------------------------------------------
__global__ __launch_bounds__(256) void attn_kernel(
    const float* __restrict__ att_en,  // (B,256,256) prescaled
    const float* __restrict__ att_de,  // (B,256,256) prescaled
    const float* __restrict__ en_seq,  // (B,256,256)
    const float* __restrict__ de_seq,  // (B,256,256)
    const float* __restrict__ nu,      // (256)
    float* __restrict__ out)           // (B,256,256)
{
    const int blk  = blockIdx.x;            // 0..1023
    const int b    = blk >> 7;
    const int t0   = (blk & 127) << 1;
    const int tid  = threadIdx.x;
    const int lane = tid & 63;
    const int wv   = __builtin_amdgcn_readfirstlane(tid >> 6);
    const int tix  = wv & 1;                // uniform
    const int uh   = wv >> 1;               // uniform
    const int lm7  = lane & 7;

    __shared__ float ae[64 * 256];          // 64KB swizzled chunk (reused stage 3)
    __shared__ float s_mup[2][2][256];      // mu partials [uh][t][e]
    __shared__ float s_al[2][256];          // alphas [t][e]

    const float* aen  = att_en + b * 65536;
    const float* ade  = att_de + (b * 256 + t0 + tix) * 256;  // uniform base
    const float* en_b = en_seq + b * 65536;

    // ---- Stage 1 ----
    for (int ec = 0; ec < 4; ++ec) {
        __syncthreads();                    // prior chunk reads done
        #pragma unroll
        for (int c = 0; c < 16; ++c) {
            const int r = wv * 16 + c;      // uniform per call
            g2lds16(aen + ((ec * 64 + r) << 8) + ((lane ^ (r & 7)) << 2),
                    &ae[(r << 8) + (lane << 2)]);
        }
        __syncthreads();                    // DMA landed (vmcnt drain)

        float acc = 0.f;
        #pragma unroll 8
        for (int g = 0; g < 32; ++g) {
            const int jj = __builtin_amdgcn_readfirstlane((uh << 5) + g);
            const int js = jj ^ lm7;
            const float4 av = *(const float4*)&ae[(lane << 8) + (js << 2)];
            const float4 dv = *(const float4*)(ade + (jj << 2));  // s_load
            const float4 nv = *(const float4*)(nu  + (jj << 2));  // s_load
            float E, r_;
            E  = __builtin_amdgcn_exp2f(av.x + dv.x);
            r_ = __builtin_amdgcn_rcpf(E + 1.f);
            acc = fmaf(nv.x, fmaf(r_, -2.f, 1.f), acc);
            E  = __builtin_amdgcn_exp2f(av.y + dv.y);
            r_ = __builtin_amdgcn_rcpf(E + 1.f);
            acc = fmaf(nv.y, fmaf(r_, -2.f, 1.f), acc);
            E  = __builtin_amdgcn_exp2f(av.z + dv.z);
            r_ = __builtin_amdgcn_rcpf(E + 1.f);
            acc = fmaf(nv.z, fmaf(r_, -2.f, 1.f), acc);
            E  = __builtin_amdgcn_exp2f(av.w + dv.w);
            r_ = __builtin_amdgcn_rcpf(E + 1.f);
            acc = fmaf(nv.w, fmaf(r_, -2.f, 1.f), acc);
        }
        s_mup[uh][tix][(ec << 6) + lane] = acc;
    }
    __syncthreads();

    // ---- Stage 2: softmax (waves 0,1 -> t = wv) ----
    if (wv < 2) {
        const int e4 = lane << 2;
        const float4 p0 = *(const float4*)&s_mup[0][wv][e4];
        const float4 p1 = *(const float4*)&s_mup[1][wv][e4];
        float4 mv;
        mv.x = p0.x + p1.x; mv.y = p0.y + p1.y;
        mv.z = p0.z + p1.z; mv.w = p0.w + p1.w;
        float m = fmaxf(fmaxf(mv.x, mv.y), fmaxf(mv.z, mv.w));
        #pragma unroll
        for (int off = 32; off > 0; off >>= 1)
            m = fmaxf(m, __shfl_xor(m, off, 64));
        const float e0 = __builtin_amdgcn_exp2f((mv.x - m) * LOG2E);
        const float e1 = __builtin_amdgcn_exp2f((mv.y - m) * LOG2E);
        const float e2 = __builtin_amdgcn_exp2f((mv.z - m) * LOG2E);
        const float e3 = __builtin_amdgcn_exp2f((mv.w - m) * LOG2E);
        float sum = (e0 + e1) + (e2 + e3);
        #pragma unroll
        for (int off = 32; off > 0; off >>= 1)
            sum += __shfl_xor(sum, off, 64);
        const float inv = __builtin_amdgcn_rcpf(sum);
        float4 al; al.x = e0 * inv; al.y = e1 * inv; al.z = e2 * inv; al.w = e3 * inv;
        *(float4*)&s_al[wv][e4] = al;
    }
    __syncthreads();

    // ---- Stage 3: wave (tix, uh) sums its e-half; partials via reused ae ----
    float* s_part = ae;                     // safe: all ae reads complete
    float4 o{0, 0, 0, 0};
    const int ebase = uh << 7;
    for (int e = 0; e < 128; ++e) {
        const float a = s_al[tix][ebase + e];                       // broadcast
        const float4 ev = *(const float4*)(en_b + ((ebase + e) << 8) + (lane << 2));
        o.x = fmaf(a, ev.x, o.x); o.y = fmaf(a, ev.y, o.y);
        o.z = fmaf(a, ev.z, o.z); o.w = fmaf(a, ev.w, o.w);
    }
    *(float4*)&s_part[(((uh << 1) | tix) << 8) + (lane << 2)] = o;
    __syncthreads();

    const float* de_b = de_seq + (b * 256 + t0) * 256;
    float* out_b      = out    + (b * 256 + t0) * 256;
    #pragma unroll
    for (int t = 0; t < 2; ++t)
        out_b[t * 256 + tid] = s_part[t * 256 + tid]
                             + s_part[(2 + t) * 256 + tid]
                             + de_b[t * 256 + tid];
}

extern "C" void kernel_launch(void* const* d_in, const int* in_sizes, int n_in,
                              void* d_out, int out_size, void* d_ws, size_t ws_size,
                              hipStream_t stream) {
    const float* en_seq = (const float*)d_in[0];
    const float* de_seq = (const float*)d_in[1];
    const float* w_en   = (const float*)d_in[2];
    const float* w_de   = (const float*)d_in[3];
    const float* nu     = (const float*)d_in[4];
    float* out = (float*)d_out;

    float* att_en = (float*)d_ws;                 // 2 MB (prescaled)
    float* att_de = att_en + 8 * 256 * 256;       // 2 MB (prescaled)

    gemm2<<<dim3(256, 2), 128, 0, stream>>>(en_seq, de_seq, w_en, w_de,
                                            att_en, att_de);
    attn_kernel<<<1024, 256, 0, stream>>>(att_en, att_de, en_seq,
                                          de_seq, nu, out);
}

// Round 6
// 128.910 us; speedup vs baseline: 1.1324x; 1.1324x over previous
//
#include <hip/hip_runtime.h>

// Problem: B=8, T_en=T_de=D=U=256.
// out = de + softmax_e( sum_u tanh(ae[b,e,u]+ad[b,t,u]) * nu[u] ) @ en
// Both projections PRESCALED by C=2*log2(e): tanh(x) = 1 - 2/exp2(C*x + C*d).
// Softmax identity: sum_u nu*tanh = SUM(nu) - 2*sum_u nu*r (r=1/(exp2+1));
// SUM(nu) is (t,e)-invariant -> drops out of softmax. Use acc=sum nu*r,
// alpha = exp2((min_acc - acc)*C) / sum.

#define C2LOG2E 2.8853900817779268f   // 2*log2(e)

// ---------------------------------------------------------------------------
// Projection GEMMs, no LDS staging for B (w is L2-resident: 512KB/XCD).
// grid 512 x 256thr. blk<256: att_enT[b][u][e] (TRANSPOSED, scaled);
// blk>=256: att_de[b][t][u] (plain, scaled).
// Block = 8 rows x 256 cols. Wave (rg=wv>>1, ch=wv&1): rows R0..R0+3,
// cols ch*128 + lane*2. A rows wave-uniform -> scalar loads.
// ---------------------------------------------------------------------------
__global__ __launch_bounds__(256) void gemm2(
    const float* __restrict__ en, const float* __restrict__ de,
    const float* __restrict__ w_en, const float* __restrict__ w_de,
    float* __restrict__ att_enT, float* __restrict__ att_de)
{
    __shared__ float st[8 * 256];      // transpose staging (en path only)

    const int isDe = blockIdx.x >> 8;
    const int rb   = blockIdx.x & 255;
    const float* x = isDe ? de : en;
    const float* w = isDe ? w_de : w_en;

    const int tid  = threadIdx.x;
    const int lane = tid & 63;
    const int wv   = __builtin_amdgcn_readfirstlane(tid >> 6);
    const int rg   = wv >> 1, ch = wv & 1;
    const int R0   = rb * 8 + rg * 4;
    const int c0   = ch * 128 + lane * 2;

    const float* xr0 = x + (R0 + 0) * 256;
    const float* xr1 = x + (R0 + 1) * 256;
    const float* xr2 = x + (R0 + 2) * 256;
    const float* xr3 = x + (R0 + 3) * 256;

    float2 a0{0,0}, a1{0,0}, a2{0,0}, a3{0,0};

    #pragma unroll 4
    for (int k = 0; k < 256; ++k) {
        const float2 wk = *(const float2*)(w + k * 256 + c0);
        const float x0 = xr0[k], x1 = xr1[k], x2 = xr2[k], x3 = xr3[k];
        a0.x = fmaf(x0, wk.x, a0.x); a0.y = fmaf(x0, wk.y, a0.y);
        a1.x = fmaf(x1, wk.x, a1.x); a1.y = fmaf(x1, wk.y, a1.y);
        a2.x = fmaf(x2, wk.x, a2.x); a2.y = fmaf(x2, wk.y, a2.y);
        a3.x = fmaf(x3, wk.x, a3.x); a3.y = fmaf(x3, wk.y, a3.y);
    }
    const float s = C2LOG2E;
    a0.x *= s; a0.y *= s; a1.x *= s; a1.y *= s;
    a2.x *= s; a2.y *= s; a3.x *= s; a3.y *= s;

    if (isDe) {
        float* y = att_de + R0 * 256 + c0;
        *(float2*)(y + 0 * 256) = a0;
        *(float2*)(y + 1 * 256) = a1;
        *(float2*)(y + 2 * 256) = a2;
        *(float2*)(y + 3 * 256) = a3;
    } else {
        // transpose 8x256 tile through LDS, store att_enT[b][u][er..er+7]
        *(float2*)&st[(rg * 4 + 0) * 256 + c0] = a0;
        *(float2*)&st[(rg * 4 + 1) * 256 + c0] = a1;
        *(float2*)&st[(rg * 4 + 2) * 256 + c0] = a2;
        *(float2*)&st[(rg * 4 + 3) * 256 + c0] = a3;
        __syncthreads();
        const int b  = rb >> 5;
        const int er = (rb & 31) * 8;
        const int u  = tid;
        float4 lo, hi;
        lo.x = st[0 * 256 + u]; lo.y = st[1 * 256 + u];
        lo.z = st[2 * 256 + u]; lo.w = st[3 * 256 + u];
        hi.x = st[4 * 256 + u]; hi.y = st[5 * 256 + u];
        hi.z = st[6 * 256 + u]; hi.w = st[7 * 256 + u];
        float* yT = att_enT + b * 65536 + u * 256 + er;
        *(float4*)(yT)     = lo;
        *(float4*)(yT + 4) = hi;
    }
}

// ---------------------------------------------------------------------------
// Attention. grid 1024 x 256thr (4KB LDS -> wave-limited occupancy).
// Block: (b = blk&7 [XCD-affine], t0 = (blk>>3)*2). Wave wv = e-quarter;
// lane = e within quarter. Each wave computes FINAL mu-acc for its 64 e's
// for BOTH t's (av load amortized x2), u-loop sequential, zero reductions.
// Stage 2: waves 0,1 softmax (min-trick). Stage 3: thread=d, both t,
// e-loop, alphas broadcast from LDS.
// ---------------------------------------------------------------------------
__global__ __launch_bounds__(256) void attn_kernel(
    const float* __restrict__ att_enT,  // (B,U,T_en) scaled
    const float* __restrict__ att_de,   // (B,T_de,U) scaled
    const float* __restrict__ en_seq,   // (B,T_en,D)
    const float* __restrict__ de_seq,   // (B,T_de,D)
    const float* __restrict__ nu,       // (U)
    float* __restrict__ out)            // (B,T_de,D)
{
    const int blk  = blockIdx.x;        // 0..1023
    const int b    = blk & 7;
    const int t0   = (blk >> 3) << 1;
    const int tid  = threadIdx.x;
    const int lane = tid & 63;
    const int wv   = __builtin_amdgcn_readfirstlane(tid >> 6);

    __shared__ float s_mu[2][256];
    __shared__ float s_al[2][256];

    const float* aw  = att_enT + b * 65536 + wv * 64 + lane;   // + u*256
    const float* ad0 = att_de + (b * 256 + t0) * 256;          // uniform
    const float* ad1 = ad0 + 256;

    // ---- Stage 1: acc[t] = sum_u nu[u] / (exp2(av+dv[t]) + 1) ----
    float acc0 = 0.f, acc1 = 0.f;
    #pragma unroll 4
    for (int u = 0; u < 256; ++u) {
        const float d0 = ad0[u];        // wave-uniform -> s_load
        const float d1 = ad1[u];        // wave-uniform -> s_load
        const float nv = nu[u];         // block-uniform -> s_load
        const float av = aw[u << 8];    // coalesced dword
        float E;
        E = __builtin_amdgcn_exp2f(av + d0);
        acc0 = fmaf(nv, __builtin_amdgcn_rcpf(E + 1.f), acc0);
        E = __builtin_amdgcn_exp2f(av + d1);
        acc1 = fmaf(nv, __builtin_amdgcn_rcpf(E + 1.f), acc1);
    }
    s_mu[0][(wv << 6) + lane] = acc0;
    s_mu[1][(wv << 6) + lane] = acc1;
    __syncthreads();

    // ---- Stage 2: softmax (logits = const - 2*acc -> use min of acc) ----
    if (wv < 2) {
        const float4 a = *(const float4*)&s_mu[wv][lane << 2];
        float mn = fminf(fminf(a.x, a.y), fminf(a.z, a.w));
        #pragma unroll
        for (int off = 32; off > 0; off >>= 1)
            mn = fminf(mn, __shfl_xor(mn, off, 64));
        const float p0 = __builtin_amdgcn_exp2f((mn - a.x) * C2LOG2E);
        const float p1 = __builtin_amdgcn_exp2f((mn - a.y) * C2LOG2E);
        const float p2 = __builtin_amdgcn_exp2f((mn - a.z) * C2LOG2E);
        const float p3 = __builtin_amdgcn_exp2f((mn - a.w) * C2LOG2E);
        float ssum = (p0 + p1) + (p2 + p3);
        #pragma unroll
        for (int off = 32; off > 0; off >>= 1)
            ssum += __shfl_xor(ssum, off, 64);
        const float inv = __builtin_amdgcn_rcpf(ssum);
        float4 al; al.x = p0 * inv; al.y = p1 * inv;
        al.z = p2 * inv; al.w = p3 * inv;
        *(float4*)&s_al[wv][lane << 2] = al;
    }
    __syncthreads();

    // ---- Stage 3: out[t][d] = de[t][d] + sum_e alpha[t][e]*en[e][d] ----
    const float* en_b = en_seq + b * 65536 + tid;
    float o0 = 0.f, o1 = 0.f;
    #pragma unroll 4
    for (int e = 0; e < 256; ++e) {
        const float A0 = s_al[0][e];    // LDS broadcast
        const float A1 = s_al[1][e];
        const float v  = en_b[e << 8];  // coalesced dword
        o0 = fmaf(A0, v, o0);
        o1 = fmaf(A1, v, o1);
    }
    const int base = (b * 256 + t0) * 256 + tid;
    out[base]       = de_seq[base]       + o0;
    out[base + 256] = de_seq[base + 256] + o1;
}

extern "C" void kernel_launch(void* const* d_in, const int* in_sizes, int n_in,
                              void* d_out, int out_size, void* d_ws, size_t ws_size,
                              hipStream_t stream) {
    const float* en_seq = (const float*)d_in[0];
    const float* de_seq = (const float*)d_in[1];
    const float* w_en   = (const float*)d_in[2];
    const float* w_de   = (const float*)d_in[3];
    const float* nu     = (const float*)d_in[4];
    float* out = (float*)d_out;

    float* att_enT = (float*)d_ws;                 // 2MB, (B,U,T_en) scaled
    float* att_de  = att_enT + 8 * 256 * 256;      // 2MB, (B,T_de,U) scaled

    gemm2<<<512, 256, 0, stream>>>(en_seq, de_seq, w_en, w_de, att_enT, att_de);
    attn_kernel<<<1024, 256, 0, stream>>>(att_enT, att_de, en_seq, de_seq,
                                          nu, out);
}

// Round 7
// 126.087 us; speedup vs baseline: 1.1578x; 1.0224x over previous
//
#include <hip/hip_runtime.h>

// Problem: B=8, T_en=T_de=D=U=256.
// out = de + softmax_e( sum_u tanh(ae[b,e,u]+ad[b,t,u]) * nu[u] ) @ en
// Projections PRESCALED by C=2*log2(e): tanh(x) = 1 - 2/exp2(ae+ad).
// Softmax identity: sum_u nu*tanh = SUM(nu) - 2*sum_u nu*r (r=1/(exp2+1));
// SUM(nu) drops out of softmax -> logits_eff = -acc, acc = sum_u nu*r.

#define C2LOG2E 2.8853900817779268f   // 2*log2(e)

// ---------------------------------------------------------------------------
// Projection GEMMs. grid 512 x 256thr: blk<256 -> att_enT[b][u][e]
// (TRANSPOSED, scaled), blk>=256 -> att_de[b][t][u] (scaled).
// Block = 8 rows x 256 cols, A-tile (8x256=8KB) in LDS; wave-uniform A
// fragments via ds_read_b128 broadcast; w coalesced float2 from L2.
// Thread: col-pair cp=tid&127 (c0=2*cp), row-half rg=tid>>7 (4 rows).
// ---------------------------------------------------------------------------
__global__ __launch_bounds__(256) void gemm2(
    const float* __restrict__ en, const float* __restrict__ de,
    const float* __restrict__ w_en, const float* __restrict__ w_de,
    float* __restrict__ att_enT, float* __restrict__ att_de)
{
    __shared__ float xs[8 * 256];      // A-tile; reused for transpose

    const int isDe = blockIdx.x >> 8;
    const int rb   = blockIdx.x & 255;
    const float* x = isDe ? de : en;
    const float* w = isDe ? w_de : w_en;

    const int tid = threadIdx.x;
    const int cp  = tid & 127;
    const int rg  = tid >> 7;          // 0 or 1
    const int c0  = cp << 1;
    const int rB  = rg << 2;           // row base in tile (0 or 4)

    // stage A-tile: 8 rows x 256 (2 float4 per thread, coalesced)
    {
        const float* xsrc = x + rb * 2048;
        *(float4*)&xs[tid * 8 + 0] = *(const float4*)(xsrc + tid * 8 + 0);
        *(float4*)&xs[tid * 8 + 4] = *(const float4*)(xsrc + tid * 8 + 4);
    }
    __syncthreads();

    float2 acc0{0,0}, acc1{0,0}, acc2{0,0}, acc3{0,0};

    #pragma unroll 4
    for (int k0 = 0; k0 < 256; k0 += 4) {
        // A fragments: uniform-address LDS broadcast (b128)
        const float4 A0 = *(const float4*)&xs[(rB + 0) * 256 + k0];
        const float4 A1 = *(const float4*)&xs[(rB + 1) * 256 + k0];
        const float4 A2 = *(const float4*)&xs[(rB + 2) * 256 + k0];
        const float4 A3 = *(const float4*)&xs[(rB + 3) * 256 + k0];
        // w rows k0..k0+3, coalesced float2
        const float2 w0 = *(const float2*)(w + (k0 + 0) * 256 + c0);
        const float2 w1 = *(const float2*)(w + (k0 + 1) * 256 + c0);
        const float2 w2 = *(const float2*)(w + (k0 + 2) * 256 + c0);
        const float2 w3 = *(const float2*)(w + (k0 + 3) * 256 + c0);

        acc0.x = fmaf(A0.x, w0.x, acc0.x); acc0.y = fmaf(A0.x, w0.y, acc0.y);
        acc1.x = fmaf(A1.x, w0.x, acc1.x); acc1.y = fmaf(A1.x, w0.y, acc1.y);
        acc2.x = fmaf(A2.x, w0.x, acc2.x); acc2.y = fmaf(A2.x, w0.y, acc2.y);
        acc3.x = fmaf(A3.x, w0.x, acc3.x); acc3.y = fmaf(A3.x, w0.y, acc3.y);

        acc0.x = fmaf(A0.y, w1.x, acc0.x); acc0.y = fmaf(A0.y, w1.y, acc0.y);
        acc1.x = fmaf(A1.y, w1.x, acc1.x); acc1.y = fmaf(A1.y, w1.y, acc1.y);
        acc2.x = fmaf(A2.y, w1.x, acc2.x); acc2.y = fmaf(A2.y, w1.y, acc2.y);
        acc3.x = fmaf(A3.y, w1.x, acc3.x); acc3.y = fmaf(A3.y, w1.y, acc3.y);

        acc0.x = fmaf(A0.z, w2.x, acc0.x); acc0.y = fmaf(A0.z, w2.y, acc0.y);
        acc1.x = fmaf(A1.z, w2.x, acc1.x); acc1.y = fmaf(A1.z, w2.y, acc1.y);
        acc2.x = fmaf(A2.z, w2.x, acc2.x); acc2.y = fmaf(A2.z, w2.y, acc2.y);
        acc3.x = fmaf(A3.z, w2.x, acc3.x); acc3.y = fmaf(A3.z, w2.y, acc3.y);

        acc0.x = fmaf(A0.w, w3.x, acc0.x); acc0.y = fmaf(A0.w, w3.y, acc0.y);
        acc1.x = fmaf(A1.w, w3.x, acc1.x); acc1.y = fmaf(A1.w, w3.y, acc1.y);
        acc2.x = fmaf(A2.w, w3.x, acc2.x); acc2.y = fmaf(A2.w, w3.y, acc2.y);
        acc3.x = fmaf(A3.w, w3.x, acc3.x); acc3.y = fmaf(A3.w, w3.y, acc3.y);
    }

    const float s = C2LOG2E;
    acc0.x *= s; acc0.y *= s; acc1.x *= s; acc1.y *= s;
    acc2.x *= s; acc2.y *= s; acc3.x *= s; acc3.y *= s;

    const int R0 = rb * 8 + rB;
    if (isDe) {
        float* y = att_de + R0 * 256 + c0;
        *(float2*)(y + 0 * 256) = acc0;
        *(float2*)(y + 1 * 256) = acc1;
        *(float2*)(y + 2 * 256) = acc2;
        *(float2*)(y + 3 * 256) = acc3;
    } else {
        // transpose 8x256 tile through LDS -> att_enT[b][u][er..er+7]
        __syncthreads();
        *(float2*)&xs[(rB + 0) * 256 + c0] = acc0;
        *(float2*)&xs[(rB + 1) * 256 + c0] = acc1;
        *(float2*)&xs[(rB + 2) * 256 + c0] = acc2;
        *(float2*)&xs[(rB + 3) * 256 + c0] = acc3;
        __syncthreads();
        const int b  = rb >> 5;
        const int er = (rb & 31) * 8;
        const int u  = tid;
        float4 lo, hi;
        lo.x = xs[0 * 256 + u]; lo.y = xs[1 * 256 + u];
        lo.z = xs[2 * 256 + u]; lo.w = xs[3 * 256 + u];
        hi.x = xs[4 * 256 + u]; hi.y = xs[5 * 256 + u];
        hi.z = xs[6 * 256 + u]; hi.w = xs[7 * 256 + u];
        float* yT = att_enT + b * 65536 + u * 256 + er;
        *(float4*)(yT)     = lo;
        *(float4*)(yT + 4) = hi;
    }
}

// ---------------------------------------------------------------------------
// Attention. grid 512 x 256thr, TT=4 decoder steps per block.
// b = blk&7 (XCD-affine: hot set per XCD < 1MB, L2-resident).
// Stage 1: wave wv owns e = wv*64+lane for ALL 4 t; av loads double-buffered
//   8-deep; att_de rows & nu wave-uniform -> s_load. Per-lane register acc.
// Stage 2: wave wv = softmax for t=wv (min-trick, Snu drops out).
// Stage 3: thread=d; alphas read as one b128 broadcast per e (s_al4[e][t]).
// ---------------------------------------------------------------------------
__global__ __launch_bounds__(256) void attn_kernel(
    const float* __restrict__ att_enT,  // (B,U,T_en) scaled
    const float* __restrict__ att_de,   // (B,T_de,U) scaled
    const float* __restrict__ en_seq,   // (B,T_en,D)
    const float* __restrict__ de_seq,   // (B,T_de,D)
    const float* __restrict__ nu,       // (U)
    float* __restrict__ out)            // (B,T_de,D)
{
    const int blk  = blockIdx.x;        // 0..511
    const int b    = blk & 7;
    const int t0   = (blk >> 3) << 2;
    const int tid  = threadIdx.x;
    const int lane = tid & 63;
    const int wv   = __builtin_amdgcn_readfirstlane(tid >> 6);

    __shared__ float s_mu[4][256];
    __shared__ float s_al4[256 * 4];    // [e][t]

    const float* aw = att_enT + b * 65536 + (wv << 6) + lane;  // + u*256
    const float* ad = att_de + (b * 256 + t0) * 256;           // 4 uniform rows

    // ---- Stage 1: acc[t] = sum_u nu[u] / (exp2(av+dv[t]) + 1) ----
    float acc0 = 0.f, acc1 = 0.f, acc2 = 0.f, acc3 = 0.f;
    float av[8], avn[8];
    #pragma unroll
    for (int j = 0; j < 8; ++j) av[j] = aw[j << 8];

    for (int u0 = 0; u0 < 256; u0 += 8) {
        if (u0 < 248) {
            #pragma unroll
            for (int j = 0; j < 8; ++j) avn[j] = aw[(u0 + 8 + j) << 8];
        }
        #pragma unroll
        for (int j = 0; j < 8; ++j) {
            const int u = u0 + j;
            const float d0 = ad[u];            // s_load (uniform)
            const float d1 = ad[256 + u];
            const float d2 = ad[512 + u];
            const float d3 = ad[768 + u];
            const float nv = nu[u];            // s_load (uniform)
            const float a  = av[j];
            float E;
            E = __builtin_amdgcn_exp2f(a + d0);
            acc0 = fmaf(nv, __builtin_amdgcn_rcpf(E + 1.f), acc0);
            E = __builtin_amdgcn_exp2f(a + d1);
            acc1 = fmaf(nv, __builtin_amdgcn_rcpf(E + 1.f), acc1);
            E = __builtin_amdgcn_exp2f(a + d2);
            acc2 = fmaf(nv, __builtin_amdgcn_rcpf(E + 1.f), acc2);
            E = __builtin_amdgcn_exp2f(a + d3);
            acc3 = fmaf(nv, __builtin_amdgcn_rcpf(E + 1.f), acc3);
        }
        #pragma unroll
        for (int j = 0; j < 8; ++j) av[j] = avn[j];
    }
    const int eidx = (wv << 6) + lane;
    s_mu[0][eidx] = acc0;
    s_mu[1][eidx] = acc1;
    s_mu[2][eidx] = acc2;
    s_mu[3][eidx] = acc3;
    __syncthreads();

    // ---- Stage 2: softmax for t = wv (logits = const - 2*acc) ----
    {
        const float4 a = *(const float4*)&s_mu[wv][lane << 2];
        float mn = fminf(fminf(a.x, a.y), fminf(a.z, a.w));
        #pragma unroll
        for (int off = 32; off > 0; off >>= 1)
            mn = fminf(mn, __shfl_xor(mn, off, 64));
        const float p0 = __builtin_amdgcn_exp2f((mn - a.x) * C2LOG2E);
        const float p1 = __builtin_amdgcn_exp2f((mn - a.y) * C2LOG2E);
        const float p2 = __builtin_amdgcn_exp2f((mn - a.z) * C2LOG2E);
        const float p3 = __builtin_amdgcn_exp2f((mn - a.w) * C2LOG2E);
        float ssum = (p0 + p1) + (p2 + p3);
        #pragma unroll
        for (int off = 32; off > 0; off >>= 1)
            ssum += __shfl_xor(ssum, off, 64);
        const float inv = __builtin_amdgcn_rcpf(ssum);
        const int e4 = lane << 2;
        s_al4[(e4 + 0) * 4 + wv] = p0 * inv;
        s_al4[(e4 + 1) * 4 + wv] = p1 * inv;
        s_al4[(e4 + 2) * 4 + wv] = p2 * inv;
        s_al4[(e4 + 3) * 4 + wv] = p3 * inv;
    }
    __syncthreads();

    // ---- Stage 3: out[t][d] = de[t][d] + sum_e alpha[t][e]*en[e][d] ----
    const float* en_b = en_seq + b * 65536 + tid;
    float o0 = 0.f, o1 = 0.f, o2 = 0.f, o3 = 0.f;
    for (int e0 = 0; e0 < 256; e0 += 8) {
        float v[8];
        #pragma unroll
        for (int j = 0; j < 8; ++j) v[j] = en_b[(e0 + j) << 8];
        #pragma unroll
        for (int j = 0; j < 8; ++j) {
            const float4 al = *(const float4*)&s_al4[(e0 + j) << 2]; // bcast
            o0 = fmaf(al.x, v[j], o0);
            o1 = fmaf(al.y, v[j], o1);
            o2 = fmaf(al.z, v[j], o2);
            o3 = fmaf(al.w, v[j], o3);
        }
    }
    const int base = (b * 256 + t0) * 256 + tid;
    out[base + 0 * 256] = de_seq[base + 0 * 256] + o0;
    out[base + 1 * 256] = de_seq[base + 1 * 256] + o1;
    out[base + 2 * 256] = de_seq[base + 2 * 256] + o2;
    out[base + 3 * 256] = de_seq[base + 3 * 256] + o3;
}

extern "C" void kernel_launch(void* const* d_in, const int* in_sizes, int n_in,
                              void* d_out, int out_size, void* d_ws, size_t ws_size,
                              hipStream_t stream) {
    const float* en_seq = (const float*)d_in[0];
    const float* de_seq = (const float*)d_in[1];
    const float* w_en   = (const float*)d_in[2];
    const float* w_de   = (const float*)d_in[3];
    const float* nu     = (const float*)d_in[4];
    float* out = (float*)d_out;

    float* att_enT = (float*)d_ws;                 // 2MB, (B,U,T_en) scaled
    float* att_de  = att_enT + 8 * 256 * 256;      // 2MB, (B,T_de,U) scaled

    gemm2<<<512, 256, 0, stream>>>(en_seq, de_seq, w_en, w_de, att_enT, att_de);
    attn_kernel<<<512, 256, 0, stream>>>(att_enT, att_de, en_seq, de_seq,
                                         nu, out);
}

// Round 8
// 123.229 us; speedup vs baseline: 1.1846x; 1.0232x over previous
//
#include <hip/hip_runtime.h>

// Problem: B=8, T_en=T_de=D=U=256.
// out = de + softmax_e( sum_u tanh(ae[b,e,u]+ad[b,t,u]) * nu[u] ) @ en
// Projections PRESCALED by C=2*log2(e): tanh(x) = 1 - 2/(exp2(sae+sad)+1).
// Softmax identity: sum_u nu*tanh = SUM(nu) - 2*acc, acc = sum_u nu/(E+1);
// SUM(nu) drops out -> logits ~ -2*acc (natural-log units), min-of-acc trick.
// 4-way rcp combine: nu0/A0+..+nu3/A3 = (n01*p23+n23*p01)/(p01*p23),
// A=E+1, p01=A0*A1, n01=nu0*E1+nu1*E0+nu0+nu1. 1 rcp per 4 u (was 4).

#define C2LOG2E 2.8853900817779268f   // 2*log2(e)

// Force a wave-uniform pointer value -> compiler can use scalar (s_load) path.
__device__ __forceinline__ const float* uptr(const float* p) {
    unsigned long long v = (unsigned long long)p;
    unsigned lo = __builtin_amdgcn_readfirstlane((unsigned)v);
    unsigned hi = __builtin_amdgcn_readfirstlane((unsigned)(v >> 32));
    return (const float*)((((unsigned long long)hi) << 32) | lo);
}

// ---------------------------------------------------------------------------
// Projection GEMMs. grid 512 x 256thr: blk<256 -> att_enT[b][u][e]
// (TRANSPOSED, scaled); blk>=256 -> att_de[b][t][u] (scaled).
// Block = 8 rows x 256 cols; wave wv owns rows r0=rb*8+wv*2 (+0,+1) with A
// read through uniform pointers (s_load, zero LDS); lanes = 4 cols (float4 w,
// full 1KB row per wave per k, L1-shared across waves). 4-deep w prefetch.
// ---------------------------------------------------------------------------
__global__ __launch_bounds__(256, 2) void gemm2(
    const float* __restrict__ en, const float* __restrict__ de,
    const float* __restrict__ w_en, const float* __restrict__ w_de,
    float* __restrict__ att_enT, float* __restrict__ att_de)
{
    __shared__ float xs[8 * 256];      // transpose staging (en path only)

    const int isDe = blockIdx.x >> 8;
    const int rb   = blockIdx.x & 255;
    const float* x = isDe ? de : en;
    const float* w = isDe ? w_de : w_en;

    const int tid  = threadIdx.x;
    const int lane = tid & 63;
    const int wv   = __builtin_amdgcn_readfirstlane(tid >> 6);
    const int r0   = rb * 8 + wv * 2;
    const int c0   = lane << 2;

    const float* ar0 = uptr(x + r0 * 256);        // uniform -> s_load
    const float* ar1 = uptr(x + r0 * 256 + 256);  // uniform -> s_load

    float4 acc0{0,0,0,0}, acc1{0,0,0,0};

    float4 wb[4], wn[4];
    #pragma unroll
    for (int j = 0; j < 4; ++j)
        wb[j] = *(const float4*)(w + j * 256 + c0);

    for (int k0 = 0; k0 < 256; k0 += 4) {
        if (k0 < 252) {
            #pragma unroll
            for (int j = 0; j < 4; ++j)
                wn[j] = *(const float4*)(w + (k0 + 4 + j) * 256 + c0);
        }
        #pragma unroll
        for (int j = 0; j < 4; ++j) {
            const int k = k0 + j;
            const float a0 = ar0[k];   // s_load
            const float a1 = ar1[k];   // s_load
            acc0.x = fmaf(a0, wb[j].x, acc0.x);
            acc0.y = fmaf(a0, wb[j].y, acc0.y);
            acc0.z = fmaf(a0, wb[j].z, acc0.z);
            acc0.w = fmaf(a0, wb[j].w, acc0.w);
            acc1.x = fmaf(a1, wb[j].x, acc1.x);
            acc1.y = fmaf(a1, wb[j].y, acc1.y);
            acc1.z = fmaf(a1, wb[j].z, acc1.z);
            acc1.w = fmaf(a1, wb[j].w, acc1.w);
        }
        #pragma unroll
        for (int j = 0; j < 4; ++j) wb[j] = wn[j];
    }

    const float s = C2LOG2E;
    acc0.x *= s; acc0.y *= s; acc0.z *= s; acc0.w *= s;
    acc1.x *= s; acc1.y *= s; acc1.z *= s; acc1.w *= s;

    if (isDe) {
        float* y = att_de + r0 * 256 + c0;
        *(float4*)(y)       = acc0;
        *(float4*)(y + 256) = acc1;
    } else {
        // transpose 8x256 tile -> att_enT[b][u][er..er+7]
        *(float4*)&xs[(wv * 2 + 0) * 256 + c0] = acc0;
        *(float4*)&xs[(wv * 2 + 1) * 256 + c0] = acc1;
        __syncthreads();
        const int b  = rb >> 5;
        const int er = (rb & 31) * 8;
        const int u  = tid;
        float4 lo, hi;
        lo.x = xs[0 * 256 + u]; lo.y = xs[1 * 256 + u];
        lo.z = xs[2 * 256 + u]; lo.w = xs[3 * 256 + u];
        hi.x = xs[4 * 256 + u]; hi.y = xs[5 * 256 + u];
        hi.z = xs[6 * 256 + u]; hi.w = xs[7 * 256 + u];
        float* yT = att_enT + b * 65536 + u * 256 + er;
        *(float4*)(yT)     = lo;
        *(float4*)(yT + 4) = hi;
    }
}

// ---------------------------------------------------------------------------
// Attention. grid 1024 x 256thr (TT=2) -> 4 blocks/CU, 16 waves/CU.
// b = blk&7 (XCD-affine: per-XCD hot set att_enT[b]+en[b] = 512KB, L2-res).
// Stage 1: wave wv owns e = wv*64+lane for both t; av 8-deep prefetch;
//   att_de/nu via uniform pointers (s_load); 4-way rcp-combined tanh-sum.
// Stage 2: waves 0,1 -> softmax for t=wv (min-trick); s_al[t][e] contiguous.
// Stage 3: thread=d; alphas as wave-uniform b128 broadcasts; en coalesced.
// ---------------------------------------------------------------------------
__global__ __launch_bounds__(256, 4) void attn_kernel(
    const float* __restrict__ att_enT,  // (B,U,T_en) scaled
    const float* __restrict__ att_de,   // (B,T_de,U) scaled
    const float* __restrict__ en_seq,   // (B,T_en,D)
    const float* __restrict__ de_seq,   // (B,T_de,D)
    const float* __restrict__ nu,       // (U)
    float* __restrict__ out)            // (B,T_de,D)
{
    const int blk  = blockIdx.x;        // 0..1023
    const int b    = blk & 7;
    const int t0   = (blk >> 3) << 1;
    const int tid  = threadIdx.x;
    const int lane = tid & 63;
    const int wv   = __builtin_amdgcn_readfirstlane(tid >> 6);

    __shared__ float s_mu[2][256];
    __shared__ float s_al[2][256];

    const float* aw  = att_enT + b * 65536 + (wv << 6) + lane;  // + u*256
    const float* ad0 = uptr(att_de + (b * 256 + t0) * 256);
    const float* ad1 = uptr(att_de + (b * 256 + t0) * 256 + 256);
    const float* nuu = uptr(nu);

    // ---- Stage 1: acc[t] = sum_u nu[u] / (exp2(av+dv[t]) + 1) ----
    float acc0 = 0.f, acc1 = 0.f;
    float av[8], avn[8];
    #pragma unroll
    for (int j = 0; j < 8; ++j) av[j] = aw[j << 8];

    for (int u0 = 0; u0 < 256; u0 += 8) {
        if (u0 < 248) {
            #pragma unroll
            for (int j = 0; j < 8; ++j) avn[j] = aw[(u0 + 8 + j) << 8];
        }
        #pragma unroll
        for (int g = 0; g < 2; ++g) {
            const int ub = u0 + g * 4;
            const float n0 = nuu[ub + 0], n1 = nuu[ub + 1];
            const float n2 = nuu[ub + 2], n3 = nuu[ub + 3];
            const float nS01 = n0 + n1, nS23 = n2 + n3;
            const float a0 = av[g * 4 + 0], a1 = av[g * 4 + 1];
            const float a2 = av[g * 4 + 2], a3 = av[g * 4 + 3];
            {   // t = t0
                const float E0 = __builtin_amdgcn_exp2f(a0 + ad0[ub + 0]);
                const float E1 = __builtin_amdgcn_exp2f(a1 + ad0[ub + 1]);
                const float E2 = __builtin_amdgcn_exp2f(a2 + ad0[ub + 2]);
                const float E3 = __builtin_amdgcn_exp2f(a3 + ad0[ub + 3]);
                const float A0 = E0 + 1.f, A1 = E1 + 1.f;
                const float A2 = E2 + 1.f, A3 = E3 + 1.f;
                const float p01 = A0 * A1, p23 = A2 * A3;
                const float n01 = fmaf(n0, E1, fmaf(n1, E0, nS01));
                const float n23 = fmaf(n2, E3, fmaf(n3, E2, nS23));
                const float num = fmaf(n23, p01, n01 * p23);
                acc0 = fmaf(num, __builtin_amdgcn_rcpf(p01 * p23), acc0);
            }
            {   // t = t0+1
                const float E0 = __builtin_amdgcn_exp2f(a0 + ad1[ub + 0]);
                const float E1 = __builtin_amdgcn_exp2f(a1 + ad1[ub + 1]);
                const float E2 = __builtin_amdgcn_exp2f(a2 + ad1[ub + 2]);
                const float E3 = __builtin_amdgcn_exp2f(a3 + ad1[ub + 3]);
                const float A0 = E0 + 1.f, A1 = E1 + 1.f;
                const float A2 = E2 + 1.f, A3 = E3 + 1.f;
                const float p01 = A0 * A1, p23 = A2 * A3;
                const float n01 = fmaf(n0, E1, fmaf(n1, E0, nS01));
                const float n23 = fmaf(n2, E3, fmaf(n3, E2, nS23));
                const float num = fmaf(n23, p01, n01 * p23);
                acc1 = fmaf(num, __builtin_amdgcn_rcpf(p01 * p23), acc1);
            }
        }
        #pragma unroll
        for (int j = 0; j < 8; ++j) av[j] = avn[j];
    }
    const int eidx = (wv << 6) + lane;
    s_mu[0][eidx] = acc0;
    s_mu[1][eidx] = acc1;
    __syncthreads();

    // ---- Stage 2: softmax for t = wv (logits = const - 2*acc) ----
    if (wv < 2) {
        const float4 a = *(const float4*)&s_mu[wv][lane << 2];
        float mn = fminf(fminf(a.x, a.y), fminf(a.z, a.w));
        #pragma unroll
        for (int off = 32; off > 0; off >>= 1)
            mn = fminf(mn, __shfl_xor(mn, off, 64));
        const float p0 = __builtin_amdgcn_exp2f((mn - a.x) * C2LOG2E);
        const float p1 = __builtin_amdgcn_exp2f((mn - a.y) * C2LOG2E);
        const float p2 = __builtin_amdgcn_exp2f((mn - a.z) * C2LOG2E);
        const float p3 = __builtin_amdgcn_exp2f((mn - a.w) * C2LOG2E);
        float ssum = (p0 + p1) + (p2 + p3);
        #pragma unroll
        for (int off = 32; off > 0; off >>= 1)
            ssum += __shfl_xor(ssum, off, 64);
        const float inv = __builtin_amdgcn_rcpf(ssum);
        float4 al; al.x = p0 * inv; al.y = p1 * inv;
        al.z = p2 * inv; al.w = p3 * inv;
        *(float4*)&s_al[wv][lane << 2] = al;   // contiguous, conflict-free
    }
    __syncthreads();

    // ---- Stage 3: out[t][d] = de[t][d] + sum_e alpha[t][e]*en[e][d] ----
    const float* en_b = en_seq + b * 65536 + tid;
    float o0 = 0.f, o1 = 0.f;
    for (int e0 = 0; e0 < 256; e0 += 8) {
        float v[8];
        #pragma unroll
        for (int j = 0; j < 8; ++j) v[j] = en_b[(e0 + j) << 8];
        #pragma unroll
        for (int q = 0; q < 2; ++q) {
            const int eb = e0 + q * 4;
            const float4 A0 = *(const float4*)&s_al[0][eb];  // uniform bcast
            const float4 A1 = *(const float4*)&s_al[1][eb];
            o0 = fmaf(A0.x, v[q*4+0], o0); o1 = fmaf(A1.x, v[q*4+0], o1);
            o0 = fmaf(A0.y, v[q*4+1], o0); o1 = fmaf(A1.y, v[q*4+1], o1);
            o0 = fmaf(A0.z, v[q*4+2], o0); o1 = fmaf(A1.z, v[q*4+2], o1);
            o0 = fmaf(A0.w, v[q*4+3], o0); o1 = fmaf(A1.w, v[q*4+3], o1);
        }
    }
    const int base = (b * 256 + t0) * 256 + tid;
    out[base]       = de_seq[base]       + o0;
    out[base + 256] = de_seq[base + 256] + o1;
}

extern "C" void kernel_launch(void* const* d_in, const int* in_sizes, int n_in,
                              void* d_out, int out_size, void* d_ws, size_t ws_size,
                              hipStream_t stream) {
    const float* en_seq = (const float*)d_in[0];
    const float* de_seq = (const float*)d_in[1];
    const float* w_en   = (const float*)d_in[2];
    const float* w_de   = (const float*)d_in[3];
    const float* nu     = (const float*)d_in[4];
    float* out = (float*)d_out;

    float* att_enT = (float*)d_ws;                 // 2MB, (B,U,T_en) scaled
    float* att_de  = att_enT + 8 * 256 * 256;      // 2MB, (B,T_de,U) scaled

    gemm2<<<512, 256, 0, stream>>>(en_seq, de_seq, w_en, w_de, att_enT, att_de);
    attn_kernel<<<1024, 256, 0, stream>>>(att_enT, att_de, en_seq, de_seq,
                                          nu, out);
}

// Round 9
// 112.545 us; speedup vs baseline: 1.2971x; 1.0949x over previous
//
#include <hip/hip_runtime.h>

// Problem: B=8, T_en=T_de=D=U=256.
// out = de + softmax_e( sum_u tanh(ae[b,e,u]+ad[b,t,u]) * nu[u] ) @ en
// tanh(x) = 1 - 2/(e^{2x}+1);  e^{2x} = Ea * sd with
//   Ea[b,e,u] = exp2(C*ae), sd[b,t,u] = exp2(C*ad), C = 2*log2(e)  (both
//   precomputed in the gemm epilogue -> attn hot loop has NO transcendentals
//   except 1 rcp per 4 u).
// Softmax identity: mu = SUM(nu) - 2*acc, acc = sum_u nu/(E+1); SUM(nu)
// drops out -> alpha = exp2((min_acc - acc)*C) / sum.
// 4-way rcp combine: sum nu_i/A_i = (n01*p23 + n23*p01) / (p01*p23),
//   A=E+1, p01=A0*A1, n01 = nu0*A1 + nu1*A0.

#define C2LOG2E 2.8853900817779268f   // 2*log2(e)

// Force a wave-uniform pointer value -> compiler can use scalar (s_load) path.
__device__ __forceinline__ const float* uptr(const float* p) {
    unsigned long long v = (unsigned long long)p;
    unsigned lo = __builtin_amdgcn_readfirstlane((unsigned)v);
    unsigned hi = __builtin_amdgcn_readfirstlane((unsigned)(v >> 32));
    return (const float*)((((unsigned long long)hi) << 32) | lo);
}

// ---------------------------------------------------------------------------
// Projection GEMMs + exp2 epilogue. grid 1024 x 256thr:
//   blk<512 : Ea packed  att_enT4[b][u>>2][e][u&3] = exp2(C * (en@w_en))
//   blk>=512: sd         att_de_exp[b][t][u]       = exp2(C * (de@w_de))
// Block = 4 rows x 256 cols. Wave wv = k-quarter [64wv,64wv+64) for ALL 4
// rows (A via uniform s_load ptrs, w as coalesced b128, 4-deep prefetch);
// partials reduced through LDS. w traffic: 256KB/block.
// ---------------------------------------------------------------------------
__global__ __launch_bounds__(256, 4) void gemm2(
    const float* __restrict__ en, const float* __restrict__ de,
    const float* __restrict__ w_en, const float* __restrict__ w_de,
    float* __restrict__ att_enT4, float* __restrict__ att_de_exp)
{
    __shared__ float part[4 * 4 * 256];   // 16KB [wave][row][col]; reused

    const int isDe = blockIdx.x >> 9;
    const int rb   = blockIdx.x & 511;
    const float* x = isDe ? de : en;
    const float* w = isDe ? w_de : w_en;

    const int tid  = threadIdx.x;
    const int lane = tid & 63;
    const int wv   = __builtin_amdgcn_readfirstlane(tid >> 6);
    const int r0   = rb * 4;
    const int c0   = lane << 2;
    const int k0   = wv << 6;

    const float* ar0 = uptr(x + (r0 + 0) * 256 + k0);
    const float* ar1 = uptr(x + (r0 + 1) * 256 + k0);
    const float* ar2 = uptr(x + (r0 + 2) * 256 + k0);
    const float* ar3 = uptr(x + (r0 + 3) * 256 + k0);
    const float* wk  = w + k0 * 256 + c0;

    float4 acc0{0,0,0,0}, acc1{0,0,0,0}, acc2{0,0,0,0}, acc3{0,0,0,0};

    float4 wb[4], wn[4];
    #pragma unroll
    for (int j = 0; j < 4; ++j)
        wb[j] = *(const float4*)(wk + j * 256);

    for (int kk = 0; kk < 64; kk += 4) {
        if (kk < 60) {
            #pragma unroll
            for (int j = 0; j < 4; ++j)
                wn[j] = *(const float4*)(wk + (kk + 4 + j) * 256);
        }
        #pragma unroll
        for (int j = 0; j < 4; ++j) {
            const int k = kk + j;
            const float a0 = ar0[k], a1 = ar1[k];   // s_load
            const float a2 = ar2[k], a3 = ar3[k];
            acc0.x = fmaf(a0, wb[j].x, acc0.x); acc0.y = fmaf(a0, wb[j].y, acc0.y);
            acc0.z = fmaf(a0, wb[j].z, acc0.z); acc0.w = fmaf(a0, wb[j].w, acc0.w);
            acc1.x = fmaf(a1, wb[j].x, acc1.x); acc1.y = fmaf(a1, wb[j].y, acc1.y);
            acc1.z = fmaf(a1, wb[j].z, acc1.z); acc1.w = fmaf(a1, wb[j].w, acc1.w);
            acc2.x = fmaf(a2, wb[j].x, acc2.x); acc2.y = fmaf(a2, wb[j].y, acc2.y);
            acc2.z = fmaf(a2, wb[j].z, acc2.z); acc2.w = fmaf(a2, wb[j].w, acc2.w);
            acc3.x = fmaf(a3, wb[j].x, acc3.x); acc3.y = fmaf(a3, wb[j].y, acc3.y);
            acc3.z = fmaf(a3, wb[j].z, acc3.z); acc3.w = fmaf(a3, wb[j].w, acc3.w);
        }
        #pragma unroll
        for (int j = 0; j < 4; ++j) wb[j] = wn[j];
    }

    // write partials [wave][row][col]
    *(float4*)&part[(wv * 4 + 0) * 256 + c0] = acc0;
    *(float4*)&part[(wv * 4 + 1) * 256 + c0] = acc1;
    *(float4*)&part[(wv * 4 + 2) * 256 + c0] = acc2;
    *(float4*)&part[(wv * 4 + 3) * 256 + c0] = acc3;
    __syncthreads();

    // reduce 4 k-partials; thread t = column; apply scale + exp2
    const int t = tid;
    float s[4];
    #pragma unroll
    for (int j = 0; j < 4; ++j) {
        const float v = part[(0 * 4 + j) * 256 + t] + part[(1 * 4 + j) * 256 + t]
                      + part[(2 * 4 + j) * 256 + t] + part[(3 * 4 + j) * 256 + t];
        s[j] = __builtin_amdgcn_exp2f(v * C2LOG2E);
    }

    if (isDe) {
        const int rr0 = (rb * 4) & 2047;   // rows within (B*T_de)
        #pragma unroll
        for (int j = 0; j < 4; ++j)
            att_de_exp[(rr0 + j) * 256 + t] = s[j];
    } else {
        const int b  = rb >> 6;
        const int er = (rb & 63) * 4;
        __syncthreads();                    // all part reads done
        #pragma unroll
        for (int j = 0; j < 4; ++j)
            part[j * 256 + t] = s[j];       // xs2[e_local][u]
        __syncthreads();
        const int ug = t >> 2;
        const int sl = t & 3;               // e_local
        const float4 v = *(const float4*)&part[sl * 256 + (ug << 2)];
        *(float4*)(att_enT4 + b * 65536 + ug * 1024 + (er + sl) * 4) = v;
    }
}

// ---------------------------------------------------------------------------
// Attention. grid 1024 x 256thr, TT=2, b = blk&7 (XCD-affine).
// Stage 1: lane = e; b128 loads of 4 packed Ea values per e (4-deep ring);
//   sd/nu via uniform s_loads; E=Ea*sd; 4-way rcp combine; NO exp2 in loop.
// Stage 2: waves 0,1 softmax (min-trick). Stage 3: thread=d, alphas as
//   uniform b128 broadcasts, en coalesced dword, 8-deep.
// ---------------------------------------------------------------------------
__global__ __launch_bounds__(256, 4) void attn_kernel(
    const float* __restrict__ att_enT4,   // (B,64,T_en,4): Ea packed
    const float* __restrict__ att_de_exp, // (B,T_de,U): sd
    const float* __restrict__ en_seq,     // (B,T_en,D)
    const float* __restrict__ de_seq,     // (B,T_de,D)
    const float* __restrict__ nu,         // (U)
    float* __restrict__ out)              // (B,T_de,D)
{
    const int blk  = blockIdx.x;          // 0..1023
    const int b    = blk & 7;
    const int t0   = (blk >> 3) << 1;
    const int tid  = threadIdx.x;
    const int lane = tid & 63;
    const int wv   = __builtin_amdgcn_readfirstlane(tid >> 6);

    __shared__ float s_mu[2][256];
    __shared__ float s_al[2][256];

    const float* aw  = att_enT4 + b * 65536 + (((wv << 6) + lane) << 2);
    const float* sd0 = uptr(att_de_exp + (b * 256 + t0) * 256);
    const float* sd1 = uptr(att_de_exp + (b * 256 + t0) * 256 + 256);
    const float* nuu = uptr(nu);

    // ---- Stage 1: acc[t] = sum_u nu[u] / (Ea*sd + 1) ----
    float acc0 = 0.f, acc1 = 0.f;
    float4 cur[4], nxt[4];
    #pragma unroll
    for (int j = 0; j < 4; ++j)
        cur[j] = *(const float4*)(aw + j * 1024);

    for (int ugb = 0; ugb < 64; ugb += 4) {
        if (ugb < 60) {
            #pragma unroll
            for (int j = 0; j < 4; ++j)
                nxt[j] = *(const float4*)(aw + (ugb + 4 + j) * 1024);
        }
        #pragma unroll
        for (int j = 0; j < 4; ++j) {
            const int ub = (ugb + j) << 2;
            const float n0 = nuu[ub + 0], n1 = nuu[ub + 1];
            const float n2 = nuu[ub + 2], n3 = nuu[ub + 3];
            const float4 Ea = cur[j];
            {   // t = t0
                const float A0 = fmaf(Ea.x, sd0[ub + 0], 1.f);
                const float A1 = fmaf(Ea.y, sd0[ub + 1], 1.f);
                const float A2 = fmaf(Ea.z, sd0[ub + 2], 1.f);
                const float A3 = fmaf(Ea.w, sd0[ub + 3], 1.f);
                const float p01 = A0 * A1, p23 = A2 * A3;
                const float n01 = fmaf(n0, A1, n1 * A0);
                const float n23 = fmaf(n2, A3, n3 * A2);
                const float num = fmaf(n01, p23, n23 * p01);
                acc0 = fmaf(num, __builtin_amdgcn_rcpf(p01 * p23), acc0);
            }
            {   // t = t0+1
                const float A0 = fmaf(Ea.x, sd1[ub + 0], 1.f);
                const float A1 = fmaf(Ea.y, sd1[ub + 1], 1.f);
                const float A2 = fmaf(Ea.z, sd1[ub + 2], 1.f);
                const float A3 = fmaf(Ea.w, sd1[ub + 3], 1.f);
                const float p01 = A0 * A1, p23 = A2 * A3;
                const float n01 = fmaf(n0, A1, n1 * A0);
                const float n23 = fmaf(n2, A3, n3 * A2);
                const float num = fmaf(n01, p23, n23 * p01);
                acc1 = fmaf(num, __builtin_amdgcn_rcpf(p01 * p23), acc1);
            }
        }
        #pragma unroll
        for (int j = 0; j < 4; ++j) cur[j] = nxt[j];
    }
    const int eidx = (wv << 6) + lane;
    s_mu[0][eidx] = acc0;
    s_mu[1][eidx] = acc1;
    __syncthreads();

    // ---- Stage 2: softmax for t = wv (logits = const - 2*acc) ----
    if (wv < 2) {
        const float4 a = *(const float4*)&s_mu[wv][lane << 2];
        float mn = fminf(fminf(a.x, a.y), fminf(a.z, a.w));
        #pragma unroll
        for (int off = 32; off > 0; off >>= 1)
            mn = fminf(mn, __shfl_xor(mn, off, 64));
        const float p0 = __builtin_amdgcn_exp2f((mn - a.x) * C2LOG2E);
        const float p1 = __builtin_amdgcn_exp2f((mn - a.y) * C2LOG2E);
        const float p2 = __builtin_amdgcn_exp2f((mn - a.z) * C2LOG2E);
        const float p3 = __builtin_amdgcn_exp2f((mn - a.w) * C2LOG2E);
        float ssum = (p0 + p1) + (p2 + p3);
        #pragma unroll
        for (int off = 32; off > 0; off >>= 1)
            ssum += __shfl_xor(ssum, off, 64);
        const float inv = __builtin_amdgcn_rcpf(ssum);
        float4 al; al.x = p0 * inv; al.y = p1 * inv;
        al.z = p2 * inv; al.w = p3 * inv;
        *(float4*)&s_al[wv][lane << 2] = al;
    }
    __syncthreads();

    // ---- Stage 3: out[t][d] = de[t][d] + sum_e alpha[t][e]*en[e][d] ----
    const float* en_b = en_seq + b * 65536 + tid;
    float o0 = 0.f, o1 = 0.f;
    for (int e0 = 0; e0 < 256; e0 += 8) {
        float v[8];
        #pragma unroll
        for (int j = 0; j < 8; ++j) v[j] = en_b[(e0 + j) << 8];
        #pragma unroll
        for (int q = 0; q < 2; ++q) {
            const int eb = e0 + q * 4;
            const float4 A0 = *(const float4*)&s_al[0][eb];  // uniform bcast
            const float4 A1 = *(const float4*)&s_al[1][eb];
            o0 = fmaf(A0.x, v[q*4+0], o0); o1 = fmaf(A1.x, v[q*4+0], o1);
            o0 = fmaf(A0.y, v[q*4+1], o0); o1 = fmaf(A1.y, v[q*4+1], o1);
            o0 = fmaf(A0.z, v[q*4+2], o0); o1 = fmaf(A1.z, v[q*4+2], o1);
            o0 = fmaf(A0.w, v[q*4+3], o0); o1 = fmaf(A1.w, v[q*4+3], o1);
        }
    }
    const int base = (b * 256 + t0) * 256 + tid;
    out[base]       = de_seq[base]       + o0;
    out[base + 256] = de_seq[base + 256] + o1;
}

extern "C" void kernel_launch(void* const* d_in, const int* in_sizes, int n_in,
                              void* d_out, int out_size, void* d_ws, size_t ws_size,
                              hipStream_t stream) {
    const float* en_seq = (const float*)d_in[0];
    const float* de_seq = (const float*)d_in[1];
    const float* w_en   = (const float*)d_in[2];
    const float* w_de   = (const float*)d_in[3];
    const float* nu     = (const float*)d_in[4];
    float* out = (float*)d_out;

    float* att_enT4   = (float*)d_ws;                // 2MB: Ea, packed
    float* att_de_exp = att_enT4 + 8 * 256 * 256;    // 2MB: sd

    gemm2<<<1024, 256, 0, stream>>>(en_seq, de_seq, w_en, w_de,
                                    att_enT4, att_de_exp);
    attn_kernel<<<1024, 256, 0, stream>>>(att_enT4, att_de_exp, en_seq,
                                          de_seq, nu, out);
}